// Round 1
// 472.858 us; speedup vs baseline: 1.1190x; 1.1190x over previous
//
#include <hip/hip_runtime.h>
#include <hip/hip_bf16.h>

typedef __attribute__((ext_vector_type(8))) short short8;
typedef __attribute__((ext_vector_type(4))) float f32x4;
using bf16 = __hip_bfloat16;

__device__ inline unsigned short f2bfu(float x) {
  bf16 h = __float2bfloat16(x);
  return __builtin_bit_cast(unsigned short, h);
}

// async global->LDS 16B copy (lands at wave-uniform base + lane*16)
__device__ __forceinline__ void gll16(const void* g, void* l) {
  __builtin_amdgcn_global_load_lds(
      (const __attribute__((address_space(1))) unsigned int*)g,
      (__attribute__((address_space(3))) unsigned int*)l, 16, 0, 0);
}

// ---------------- cast fp32 -> bf16, 4 elems/thread ----------------
__global__ __launch_bounds__(256) void cast_f32_bf16(const float4* __restrict__ src,
                                                     unsigned long long* __restrict__ dst,
                                                     int n4) {
  int i = blockIdx.x * 256 + threadIdx.x;
  if (i >= n4) return;
  float4 v = src[i];
  unsigned long long r = (unsigned long long)f2bfu(v.x)
                       | ((unsigned long long)f2bfu(v.y) << 16)
                       | ((unsigned long long)f2bfu(v.z) << 32)
                       | ((unsigned long long)f2bfu(v.w) << 48);
  dst[i] = r;
}

// ---------------- GEMM: C[M,N] = A[M,K] * B[N,K]^T ----------------
// 256x256 tile, BK=64, 8 waves (2Mx4N), 8-phase schedule with counted vmcnt,
// XOR-swizzled LDS via pre-swizzled global_load_lds sources (involution on bits 4-6).
__device__ inline void store_cvt(float* p, float v) { *p = v; }
__device__ inline void store_cvt(bf16* p, float v) { *p = __float2bfloat16(v); }

template <typename OutT>
__global__ __launch_bounds__(512, 2) void gemm_bt(const bf16* __restrict__ A,
                                                  const bf16* __restrict__ B,
                                                  OutT* __restrict__ C,
                                                  int M, int N, int K) {
  __shared__ __align__(16) bf16 lds[2][2][256 * 64];  // [op A/B][dbuf][256 rows][64 k] = 128 KiB
  const int tid = threadIdx.x;
  const int wave = tid >> 6, lane = tid & 63;
  const int wm = wave >> 2, wn = wave & 3;          // 2 M-waves x 4 N-waves; per-wave 128x64 out
  const int quad = lane >> 4, l16 = lane & 15;

  // XCD-aware swizzle (nwg % 8 == 0 for all our shapes -> simple form is bijective)
  const int nwg = gridDim.x * gridDim.y;
  int lin = blockIdx.y * gridDim.x + blockIdx.x;
  lin = (lin & 7) * (nwg >> 3) + (lin >> 3);
  const int n0 = (lin % gridDim.x) << 8;
  const int m0 = (lin / gridDim.x) << 8;

  // staging pattern: pass p writes LDS chunk (p*512+tid)*16 LINEARLY (gll requirement);
  // source is pre-swizzled with the same involution the reads use: byte ^= (row&7)<<4.
  int off_el[2], dst_b[2];
#pragma unroll
  for (int p = 0; p < 2; p++) {
    int d = (p * 512 + tid) * 16;
    int dl = d ^ (((d >> 7) & 7) << 4);
    off_el[p] = (dl >> 7) * K + ((dl & 127) >> 1);
    dst_b[p] = d;
  }

  auto STAGE = [&](const bf16* __restrict__ P, int op, int bfi, int half, int rowBase, int kt) {
    const bf16* src = P + (size_t)rowBase * K + kt;
    char* dst = (char*)&lds[op][bfi][half * 8192];
    gll16(src + off_el[0], dst + dst_b[0]);
    gll16(src + off_el[1], dst + dst_b[1]);
  };
  auto FRAG = [&](int op, int bfi, int row, int cb) -> short8 {
    int byteoff = ((row << 7) + cb) ^ ((row & 7) << 4);
    return *(const short8*)((const char*)&lds[op][bfi][0] + byteoff);
  };

  f32x4 acc[8][4] = {};
  const int nkt = K >> 6;

  // prologue: tile0 all 4 half-tiles + tile1 A halves; then wait all but newest 4
  STAGE(A, 0, 0, 0, m0, 0);
  STAGE(A, 0, 0, 1, m0 + 128, 0);
  STAGE(B, 1, 0, 0, n0, 0);
  STAGE(B, 1, 0, 1, n0 + 128, 0);
  {
    const int k1 = (nkt > 1) ? 64 : 0;
    STAGE(A, 0, 1, 0, m0, k1);
    STAGE(A, 0, 1, 1, m0 + 128, k1);
  }
  asm volatile("s_waitcnt vmcnt(4)" ::: "memory");
  __builtin_amdgcn_s_barrier();
  __builtin_amdgcn_sched_barrier(0);

  for (int t = 0; t < nkt; ++t) {
    const int bfi = t & 1, nbf = bfi ^ 1;
    const int kt1 = min(t + 1, nkt - 1) << 6;
    const int kt2 = min(t + 2, nkt - 1) << 6;
    short8 alo[4][2], ahi[4][2], b01[2][2], b23[2][2];

    // ---- phase 0: read A-lo + B n01; stage t+1 B-top & B-bot; MFMA (mlo x n01)
#pragma unroll
    for (int mf = 0; mf < 4; mf++)
#pragma unroll
      for (int ks = 0; ks < 2; ks++)
        alo[mf][ks] = FRAG(0, bfi, wm * 128 + mf * 16 + l16, ks * 64 + quad * 16);
#pragma unroll
    for (int nf = 0; nf < 2; nf++)
#pragma unroll
      for (int ks = 0; ks < 2; ks++)
        b01[nf][ks] = FRAG(1, bfi, wn * 64 + nf * 16 + l16, ks * 64 + quad * 16);
    STAGE(B, 1, nbf, 0, n0, kt1);
    STAGE(B, 1, nbf, 1, n0 + 128, kt1);
    __builtin_amdgcn_s_barrier();
    asm volatile("s_waitcnt lgkmcnt(0)" ::: "memory");
    __builtin_amdgcn_sched_barrier(0);
    __builtin_amdgcn_s_setprio(1);
#pragma unroll
    for (int mf = 0; mf < 4; mf++)
#pragma unroll
      for (int nf = 0; nf < 2; nf++)
#pragma unroll
        for (int ks = 0; ks < 2; ks++)
          acc[mf][nf] = __builtin_amdgcn_mfma_f32_16x16x32_bf16(alo[mf][ks], b01[nf][ks], acc[mf][nf], 0, 0, 0);
    __builtin_amdgcn_s_setprio(0);
    __builtin_amdgcn_sched_barrier(0);
    __builtin_amdgcn_s_barrier();
    __builtin_amdgcn_sched_barrier(0);

    // ---- phase 1: read A-hi; MFMA (mhi x n01)
#pragma unroll
    for (int mf = 0; mf < 4; mf++)
#pragma unroll
      for (int ks = 0; ks < 2; ks++)
        ahi[mf][ks] = FRAG(0, bfi, wm * 128 + 64 + mf * 16 + l16, ks * 64 + quad * 16);
    __builtin_amdgcn_s_barrier();
    asm volatile("s_waitcnt lgkmcnt(0)" ::: "memory");
    __builtin_amdgcn_sched_barrier(0);
    __builtin_amdgcn_s_setprio(1);
#pragma unroll
    for (int mf = 0; mf < 4; mf++)
#pragma unroll
      for (int nf = 0; nf < 2; nf++)
#pragma unroll
        for (int ks = 0; ks < 2; ks++)
          acc[4 + mf][nf] = __builtin_amdgcn_mfma_f32_16x16x32_bf16(ahi[mf][ks], b01[nf][ks], acc[4 + mf][nf], 0, 0, 0);
    __builtin_amdgcn_s_setprio(0);
    __builtin_amdgcn_sched_barrier(0);
    __builtin_amdgcn_s_barrier();
    __builtin_amdgcn_sched_barrier(0);

    // ---- phase 2: read B n23; stage t+2 A-top (A regions free after phase 1); MFMA (mhi x n23)
#pragma unroll
    for (int nf = 0; nf < 2; nf++)
#pragma unroll
      for (int ks = 0; ks < 2; ks++)
        b23[nf][ks] = FRAG(1, bfi, wn * 64 + 32 + nf * 16 + l16, ks * 64 + quad * 16);
    STAGE(A, 0, bfi, 0, m0, kt2);
    __builtin_amdgcn_s_barrier();
    asm volatile("s_waitcnt lgkmcnt(0)" ::: "memory");
    __builtin_amdgcn_sched_barrier(0);
    __builtin_amdgcn_s_setprio(1);
#pragma unroll
    for (int mf = 0; mf < 4; mf++)
#pragma unroll
      for (int nf = 0; nf < 2; nf++)
#pragma unroll
        for (int ks = 0; ks < 2; ks++)
          acc[4 + mf][2 + nf] = __builtin_amdgcn_mfma_f32_16x16x32_bf16(ahi[mf][ks], b23[nf][ks], acc[4 + mf][2 + nf], 0, 0, 0);
    __builtin_amdgcn_s_setprio(0);
    __builtin_amdgcn_sched_barrier(0);
    __builtin_amdgcn_s_barrier();
    __builtin_amdgcn_sched_barrier(0);

    // ---- phase 3: stage t+2 A-bot; MFMA (mlo x n23); counted vmcnt once per K-tile
    STAGE(A, 0, bfi, 1, m0 + 128, kt2);
    __builtin_amdgcn_s_barrier();
    __builtin_amdgcn_sched_barrier(0);
    __builtin_amdgcn_s_setprio(1);
#pragma unroll
    for (int mf = 0; mf < 4; mf++)
#pragma unroll
      for (int nf = 0; nf < 2; nf++)
#pragma unroll
        for (int ks = 0; ks < 2; ks++)
          acc[mf][2 + nf] = __builtin_amdgcn_mfma_f32_16x16x32_bf16(alo[mf][ks], b23[nf][ks], acc[mf][2 + nf], 0, 0, 0);
    __builtin_amdgcn_s_setprio(0);
    __builtin_amdgcn_sched_barrier(0);
    asm volatile("s_waitcnt vmcnt(4)" ::: "memory");  // newest 4 = t+2 A stages; t+1 fully landed
    __builtin_amdgcn_s_barrier();
    __builtin_amdgcn_sched_barrier(0);
  }

  // epilogue
#pragma unroll
  for (int mf = 0; mf < 8; mf++)
#pragma unroll
    for (int nf = 0; nf < 4; nf++) {
      int col = n0 + wn * 64 + nf * 16 + l16;
#pragma unroll
      for (int r = 0; r < 4; r++) {
        int row = m0 + wm * 128 + mf * 16 + quad * 4 + r;
        store_cvt(&C[(size_t)row * N + col], acc[mf][nf][r]);
      }
    }
}

// ---------------- RMSNorm + RoPE: one wave per (token, slot) row ----------------
// rows = slot*8192 + token, slots 0..19 (16 q + 4 k). V is handled by transpose_v.
// Lane holds d=lane and d=lane+64 — rope partner is in-lane, one sincos per lane.
__global__ __launch_bounds__(256) void norm_rope(const bf16* __restrict__ qkv,
                                                 bf16* __restrict__ qb,
                                                 bf16* __restrict__ kb) {
  const int lane = threadIdx.x & 63;
  const int gw = (blockIdx.x * 256 + threadIdx.x) >> 6;
  const int nw = (gridDim.x * 256) >> 6;
  const float inv_freq = __expf(-(float)lane * (9.210340371976184f / 64.0f));
  for (int row = gw; row < 20 * 8192; row += nw) {
    const int slot = row >> 13, token = row & 8191;
    const int b = token >> 11, t = token & 2047;
    const bf16* src = qkv + (size_t)token * 3072 + slot * 128;
    float x1 = __bfloat162float(src[lane]);
    float x2 = __bfloat162float(src[lane + 64]);
    float ss = x1 * x1 + x2 * x2;
#pragma unroll
    for (int m = 1; m < 64; m <<= 1) ss += __shfl_xor(ss, m, 64);
    float rinv = rsqrtf(ss * (1.0f / 128.0f) + 1.1920929e-7f);
    x1 *= rinv; x2 *= rinv;
    float c, s;
    __sincosf((float)t * inv_freq, &s, &c);
    float o1 = x1 * c + x2 * s;
    float o2 = x2 * c - x1 * s;
    bf16* dst;
    if (slot < 16) {
      o1 *= 0.08838834764831845f;  // fold 1/sqrt(D) into q
      o2 *= 0.08838834764831845f;
      dst = qb + (((size_t)(b * 16 + slot)) * 2048 + t) * 128;
    } else {
      dst = kb + (((size_t)(b * 4 + (slot - 16))) * 2048 + t) * 128;
    }
    dst[lane] = __float2bfloat16(o1);
    dst[lane + 64] = __float2bfloat16(o2);
  }
}

// ---------------- V transpose straight from qkv: -> (s, d, t), s = b*4+hkv ----------------
__global__ __launch_bounds__(256) void transpose_v(const bf16* __restrict__ qkv,
                                                   bf16* __restrict__ vout) {
  __shared__ __align__(16) bf16 til[64][144];
  const int tid = threadIdx.x;
  const int s = blockIdx.y;                 // b*4 + hkv
  const int b = s >> 2, hkv = s & 3;
  const bf16* src = qkv + ((size_t)(b * 2048 + blockIdx.x * 64)) * 3072 + 2560 + hkv * 128;
  bf16* dst = vout + (size_t)s * 128 * 2048 + blockIdx.x * 64;
#pragma unroll
  for (int p = 0; p < 4; p++) {
    int idx = p * 256 + tid;
    *(uint4*)&til[idx >> 4][(idx & 15) * 8] =
        *(const uint4*)&src[(size_t)(idx >> 4) * 3072 + (idx & 15) * 8];
  }
  __syncthreads();
  const int ds = tid & 127;
  const int hs = tid >> 7;
#pragma unroll
  for (int p = 0; p < 4; p++) {
    int c8 = (p * 2 + hs) * 8;
    short8 v;
#pragma unroll
    for (int j = 0; j < 8; j++) v[j] = *(const short*)&til[c8 + j][ds];
    *(short8*)&dst[(size_t)ds * 2048 + c8] = v;
  }
}

// ---------------- causal GQA flash attention (persistent, balanced) ----------------
// 512 blocks = exactly 2/CU. Block i processes items {i, 1023-i}; item = qt*64 + bh.
// qt pairs sum to 15 => every block runs exactly 34 K-tiles. Fixed-shift softmax.
__global__ __launch_bounds__(512, 4) void flash_attn(const bf16* __restrict__ qb,
                                                     const bf16* __restrict__ kb,
                                                     const bf16* __restrict__ vtg,
                                                     bf16* __restrict__ attnb) {
  __shared__ __align__(16) bf16 Ks[64][136];    // 17.4 KB
  __shared__ __align__(16) bf16 Vt[128][72];    // 18.4 KB  [d][t]
  __shared__ __align__(16) bf16 Ps[8][16][72];  // 18.4 KB  per-wave slab

  const int tid = threadIdx.x;
  const int w = tid >> 6, lane = tid & 63;
  const int quad = lane >> 4, l16 = lane & 15;
  const int krow = tid >> 4, kc8 = (tid & 15) * 8;
  const int vrow = tid >> 3, vc8 = (tid & 7) * 8;

  for (int it = 0; it < 2; it++) {
    const int item = it == 0 ? blockIdx.x : 1023 - blockIdx.x;
    const int qt = item >> 6, bh = item & 63;
    const int b = bh >> 4, h = bh & 15, hkv = h >> 2;
    const int q0 = qt * 128;
    const bf16* Q  = qb  + ((size_t)(b * 16 + h) * 2048 + q0) * 128;
    const bf16* Kp = kb  + (size_t)(b * 4 + hkv) * 2048 * 128;
    const bf16* Vg = vtg + (size_t)(b * 4 + hkv) * 128 * 2048;
    const int qw = q0 + w * 16;

    // Q fragments (A-layout), pre-scaled by 1/sqrt(D)
    short8 aq[4];
#pragma unroll
    for (int dk = 0; dk < 4; dk++)
      aq[dk] = *(const short8*)&Q[(size_t)(w * 16 + l16) * 128 + dk * 32 + quad * 8];

    f32x4 o[8] = {};
    float l_i[4] = {0.f, 0.f, 0.f, 0.f};

    const int ntiles = 2 * qt + 2;
    uint4 ka0 = *(const uint4*)&Kp[(size_t)krow * 128 + kc8];
    uint4 ka1 = *(const uint4*)&Kp[(size_t)(krow + 32) * 128 + kc8];
    uint4 va0 = *(const uint4*)&Vg[(size_t)vrow * 2048 + vc8];
    uint4 va1 = *(const uint4*)&Vg[(size_t)(vrow + 64) * 2048 + vc8];

    for (int kt = 0; kt < ntiles; kt++) {
      const int kv0 = kt * 64;
      *(uint4*)&Ks[krow][kc8]      = ka0;
      *(uint4*)&Ks[krow + 32][kc8] = ka1;
      *(uint4*)&Vt[vrow][vc8]      = va0;
      *(uint4*)&Vt[vrow + 64][vc8] = va1;
      __syncthreads();

      // prefetch next tile; flies during compute
      const int nkv0 = min(kv0 + 64, (ntiles - 1) * 64);
      ka0 = *(const uint4*)&Kp[(size_t)(nkv0 + krow) * 128 + kc8];
      ka1 = *(const uint4*)&Kp[(size_t)(nkv0 + krow + 32) * 128 + kc8];
      va0 = *(const uint4*)&Vg[(size_t)vrow * 2048 + nkv0 + vc8];
      va1 = *(const uint4*)&Vg[(size_t)(vrow + 64) * 2048 + nkv0 + vc8];

      if (kv0 <= qw + 15) {  // wave-uniform causal skip
        f32x4 s[4] = {};
#pragma unroll
        for (int nt = 0; nt < 4; nt++)
#pragma unroll
          for (int dk = 0; dk < 4; dk++) {
            short8 bk = *(const short8*)&Ks[nt * 16 + l16][dk * 32 + quad * 8];
            s[nt] = __builtin_amdgcn_mfma_f32_16x16x32_bf16(aq[dk], bk, s[nt], 0, 0, 0);
          }

        // fixed-shift softmax: RMS-normed q,k => |s| <= sqrt(128) < 12
        const bool dtile = (kv0 + 63 > qw);
        const int qrow = qw + quad * 4;
#pragma unroll
        for (int nt = 0; nt < 4; nt++) {
          const int kcol = kv0 + nt * 16 + l16;
#pragma unroll
          for (int r = 0; r < 4; r++) {
            float p = __expf(s[nt][r] - 12.0f);
            if (dtile && kcol > qrow + r) p = 0.f;
            l_i[r] += p;
            Ps[w][quad * 4 + r][nt * 16 + l16] = __float2bfloat16(p);
          }
        }
        __threadfence_block();  // intra-wave RAW on per-wave Ps slab

        short8 ap[2];
#pragma unroll
        for (int kk = 0; kk < 2; kk++)
          ap[kk] = *(const short8*)&Ps[w][l16][kk * 32 + quad * 8];
#pragma unroll
        for (int vt = 0; vt < 8; vt++)
#pragma unroll
          for (int kk = 0; kk < 2; kk++) {
            short8 bv = *(const short8*)&Vt[vt * 16 + l16][kk * 32 + quad * 8];
            o[vt] = __builtin_amdgcn_mfma_f32_16x16x32_bf16(ap[kk], bv, o[vt], 0, 0, 0);
          }
      }
      __syncthreads();
    }

    // epilogue: register-only (safe to overlap with next item's staging)
#pragma unroll
    for (int r = 0; r < 4; r++) {
#pragma unroll
      for (int mm = 1; mm < 16; mm <<= 1) l_i[r] += __shfl_xor(l_i[r], mm, 64);
    }
#pragma unroll
    for (int r = 0; r < 4; r++) {
      float inv = 1.0f / l_i[r];
      int trow = qw + quad * 4 + r;
      size_t base = ((size_t)b * 2048 + trow) * 2048 + h * 128;
#pragma unroll
      for (int vt = 0; vt < 8; vt++)
        attnb[base + vt * 16 + l16] = __float2bfloat16(o[vt][r] * inv);
    }
  }
}

__global__ void finalize(float* out) {
  if (threadIdx.x == 0 && blockIdx.x == 0) out[(size_t)8192 * 2048] = 0.0f;
}

extern "C" void kernel_launch(void* const* d_in, const int* in_sizes, int n_in,
                              void* d_out, int out_size, void* d_ws, size_t ws_size,
                              hipStream_t stream) {
  const float* x  = (const float*)d_in[0];
  const float* Wq = (const float*)d_in[1];
  const float* Wk = (const float*)d_in[2];
  const float* Wv = (const float*)d_in[3];
  const float* Wo = (const float*)d_in[4];
  float* out = (float*)d_out;

  char* ws = (char*)d_ws;
  bf16* xb    = (bf16*)(ws);               // 33.5 MB
  bf16* wqkv  = (bf16*)(ws + 33554432);    // 12.6 MB (dead after QKV gemm)
  bf16* vtb   = (bf16*)(ws + 33554432);    // 8.4 MB, aliases wqkv
  bf16* wob   = (bf16*)(ws + 46137344);    // 8.4 MB
  bf16* qkvb  = (bf16*)(ws + 54525952);    // 50.3 MB
  bf16* qb    = (bf16*)(ws + 104857600);   // 33.5 MB
  bf16* kb    = (bf16*)(ws + 138412032);   // 8.4 MB
  bf16* attnb = qkvb;                      // alias: qkv dead after attention inputs built

  cast_f32_bf16<<<16384, 256, 0, stream>>>((const float4*)x,  (unsigned long long*)xb, 4194304);
  cast_f32_bf16<<<4096,  256, 0, stream>>>((const float4*)Wq, (unsigned long long*)wqkv, 1048576);
  cast_f32_bf16<<<1024,  256, 0, stream>>>((const float4*)Wk, (unsigned long long*)(wqkv + 2048 * 2048), 262144);
  cast_f32_bf16<<<1024,  256, 0, stream>>>((const float4*)Wv, (unsigned long long*)(wqkv + 2560 * 2048), 262144);
  cast_f32_bf16<<<4096,  256, 0, stream>>>((const float4*)Wo, (unsigned long long*)wob, 1048576);

  gemm_bt<bf16><<<dim3(12, 32), 512, 0, stream>>>(xb, wqkv, qkvb, 8192, 3072, 2048);
  norm_rope<<<4096, 256, 0, stream>>>(qkvb, qb, kb);
  transpose_v<<<dim3(32, 16), 256, 0, stream>>>(qkvb, vtb);
  flash_attn<<<512, 512, 0, stream>>>(qb, kb, vtb, attnb);
  gemm_bt<float><<<dim3(8, 32), 512, 0, stream>>>(attnb, wob, out, 8192, 2048, 2048);
  finalize<<<1, 64, 0, stream>>>(out);
}

// Round 3
// 468.339 us; speedup vs baseline: 1.1298x; 1.0097x over previous
//
#include <hip/hip_runtime.h>
#include <hip/hip_bf16.h>

typedef __attribute__((ext_vector_type(8))) short short8;
typedef __attribute__((ext_vector_type(4))) float f32x4;
using bf16 = __hip_bfloat16;

__device__ inline unsigned short f2bfu(float x) {
  bf16 h = __float2bfloat16(x);
  return __builtin_bit_cast(unsigned short, h);
}

// async global->LDS 16B copy (lands at wave-uniform base + lane*16)
__device__ __forceinline__ void gll16(const void* g, void* l) {
  __builtin_amdgcn_global_load_lds(
      (const __attribute__((address_space(1))) unsigned int*)g,
      (__attribute__((address_space(3))) unsigned int*)l, 16, 0, 0);
}

// ---------------- cast fp32 -> bf16, 4 elems/thread ----------------
__global__ __launch_bounds__(256) void cast_f32_bf16(const float4* __restrict__ src,
                                                     unsigned long long* __restrict__ dst,
                                                     int n4) {
  int i = blockIdx.x * 256 + threadIdx.x;
  if (i >= n4) return;
  float4 v = src[i];
  unsigned long long r = (unsigned long long)f2bfu(v.x)
                       | ((unsigned long long)f2bfu(v.y) << 16)
                       | ((unsigned long long)f2bfu(v.z) << 32)
                       | ((unsigned long long)f2bfu(v.w) << 48);
  dst[i] = r;
}

// ---------------- GEMM: C[M,N] = A[M,K] * B[N,K]^T ----------------
// 256x256 tile, BK=64, 8 waves (2Mx4N). Read-ahead pipelined 4-phase schedule:
// ds_reads for phase i+1 issued in phase i (counted lgkmcnt), staging 2 K-tiles
// deep (counted vmcnt(4), never drained to 0 in-loop). Cross-wave visibility of
// staged tiles: every vmcnt drain is followed by s_barrier BEFORE any wave reads
// the staged region. XOR-swizzled LDS via pre-swizzled global_load_lds sources.
__device__ inline void store_cvt(float* p, float v) { *p = v; }
__device__ inline void store_cvt(bf16* p, float v) { *p = __float2bfloat16(v); }

template <typename OutT>
__global__ __launch_bounds__(512, 2) void gemm_bt(const bf16* __restrict__ A,
                                                  const bf16* __restrict__ B,
                                                  OutT* __restrict__ C,
                                                  int M, int N, int K) {
  __shared__ __align__(16) bf16 lds[2][2][256 * 64];  // [op A/B][dbuf][256 rows][64 k] = 128 KiB
  const int tid = threadIdx.x;
  const int wave = tid >> 6, lane = tid & 63;
  const int wm = wave >> 2, wn = wave & 3;          // 2 M-waves x 4 N-waves; per-wave 128x64 out
  const int quad = lane >> 4, l16 = lane & 15;

  // XCD-aware swizzle (nwg % 8 == 0 for all our shapes -> simple form is bijective)
  const int nwg = gridDim.x * gridDim.y;
  int lin = blockIdx.y * gridDim.x + blockIdx.x;
  lin = (lin & 7) * (nwg >> 3) + (lin >> 3);
  const int n0 = (lin % gridDim.x) << 8;
  const int m0 = (lin / gridDim.x) << 8;

  // staging pattern: pass p writes LDS chunk (p*512+tid)*16 LINEARLY (gll requirement);
  // source is pre-swizzled with the same involution the reads use: byte ^= (row&7)<<4.
  int off_el[2], dst_b[2];
#pragma unroll
  for (int p = 0; p < 2; p++) {
    int d = (p * 512 + tid) * 16;
    int dl = d ^ (((d >> 7) & 7) << 4);
    off_el[p] = (dl >> 7) * K + ((dl & 127) >> 1);
    dst_b[p] = d;
  }

  auto STAGE = [&](const bf16* __restrict__ P, int op, int bfi, int half, int rowBase, int kt) {
    const bf16* src = P + (size_t)rowBase * K + kt;
    char* dst = (char*)&lds[op][bfi][half * 8192];
    gll16(src + off_el[0], dst + dst_b[0]);
    gll16(src + off_el[1], dst + dst_b[1]);
  };
  auto FRAG = [&](int op, int bfi, int row, int cb) -> short8 {
    int byteoff = ((row << 7) + cb) ^ ((row & 7) << 4);
    return *(const short8*)((const char*)&lds[op][bfi][0] + byteoff);
  };

  f32x4 acc[8][4] = {};
  const int nkt = K >> 6;

  short8 alo[4][2], ahi[4][2], b01[2][2], b23[2][2];

  // prologue: stage tile0 + tile1 fully (16 loads); wait tile0 + barrier; preload alo,b01.
  STAGE(A, 0, 0, 0, m0, 0);
  STAGE(A, 0, 0, 1, m0 + 128, 0);
  STAGE(B, 1, 0, 0, n0, 0);
  STAGE(B, 1, 0, 1, n0 + 128, 0);
  {
    const int k1 = (nkt > 1) ? 64 : 0;
    STAGE(A, 0, 1, 0, m0, k1);
    STAGE(A, 0, 1, 1, m0 + 128, k1);
    STAGE(B, 1, 1, 0, n0, k1);
    STAGE(B, 1, 1, 1, n0 + 128, k1);
  }
  asm volatile("s_waitcnt vmcnt(8)" ::: "memory");
  __builtin_amdgcn_s_barrier();
  __builtin_amdgcn_sched_barrier(0);
#pragma unroll
  for (int mf = 0; mf < 4; mf++)
#pragma unroll
    for (int ks = 0; ks < 2; ks++)
      alo[mf][ks] = FRAG(0, 0, wm * 128 + mf * 16 + l16, ks * 64 + quad * 16);
#pragma unroll
  for (int nf = 0; nf < 2; nf++)
#pragma unroll
    for (int ks = 0; ks < 2; ks++)
      b01[nf][ks] = FRAG(1, 0, wn * 64 + nf * 16 + l16, ks * 64 + quad * 16);

  for (int t = 0; t < nkt; ++t) {
    const int bfi = t & 1, nbf = bfi ^ 1;
    const int kt2 = min(t + 2, nkt - 1) << 6;

    // ---- p0: issue ahi reads; MFMA mlo x n01 (alo,b01 drained by lgkm(8))
#pragma unroll
    for (int mf = 0; mf < 4; mf++)
#pragma unroll
      for (int ks = 0; ks < 2; ks++)
        ahi[mf][ks] = FRAG(0, bfi, wm * 128 + 64 + mf * 16 + l16, ks * 64 + quad * 16);
    asm volatile("s_waitcnt lgkmcnt(8)" ::: "memory");
    __builtin_amdgcn_sched_barrier(0);
    __builtin_amdgcn_s_setprio(1);
#pragma unroll
    for (int mf = 0; mf < 4; mf++)
#pragma unroll
      for (int nf = 0; nf < 2; nf++)
#pragma unroll
        for (int ks = 0; ks < 2; ks++)
          acc[mf][nf] = __builtin_amdgcn_mfma_f32_16x16x32_bf16(alo[mf][ks], b01[nf][ks], acc[mf][nf], 0, 0, 0);
    __builtin_amdgcn_s_setprio(0);
    __builtin_amdgcn_sched_barrier(0);
    __builtin_amdgcn_s_barrier();
    __builtin_amdgcn_sched_barrier(0);

    // ---- p1: issue b23 reads; MFMA mhi x n01 (ahi drained by lgkm(4))
#pragma unroll
    for (int nf = 0; nf < 2; nf++)
#pragma unroll
      for (int ks = 0; ks < 2; ks++)
        b23[nf][ks] = FRAG(1, bfi, wn * 64 + 32 + nf * 16 + l16, ks * 64 + quad * 16);
    asm volatile("s_waitcnt lgkmcnt(4)" ::: "memory");
    __builtin_amdgcn_sched_barrier(0);
    __builtin_amdgcn_s_setprio(1);
#pragma unroll
    for (int mf = 0; mf < 4; mf++)
#pragma unroll
      for (int nf = 0; nf < 2; nf++)
#pragma unroll
        for (int ks = 0; ks < 2; ks++)
          acc[4 + mf][nf] = __builtin_amdgcn_mfma_f32_16x16x32_bf16(ahi[mf][ks], b01[nf][ks], acc[4 + mf][nf], 0, 0, 0);
    __builtin_amdgcn_s_setprio(0);
    __builtin_amdgcn_sched_barrier(0);
    __builtin_amdgcn_s_barrier();
    __builtin_amdgcn_sched_barrier(0);

    // ---- p2: stage A<-t+2 (A[bfi] fully consumed: alo pre-loop/p3, ahi drained p1,
    //          p1 end barrier passed); MFMA mhi x n23 (b23 drained by lgkm(0))
    STAGE(A, 0, bfi, 0, m0, kt2);
    STAGE(A, 0, bfi, 1, m0 + 128, kt2);
    asm volatile("s_waitcnt lgkmcnt(0)" ::: "memory");
    __builtin_amdgcn_sched_barrier(0);
    __builtin_amdgcn_s_setprio(1);
#pragma unroll
    for (int mf = 0; mf < 4; mf++)
#pragma unroll
      for (int nf = 0; nf < 2; nf++)
#pragma unroll
        for (int ks = 0; ks < 2; ks++)
          acc[4 + mf][2 + nf] = __builtin_amdgcn_mfma_f32_16x16x32_bf16(ahi[mf][ks], b23[nf][ks], acc[4 + mf][2 + nf], 0, 0, 0);
    __builtin_amdgcn_s_setprio(0);
    __builtin_amdgcn_sched_barrier(0);
    __builtin_amdgcn_s_barrier();
    __builtin_amdgcn_sched_barrier(0);

    // ---- p3: vmcnt(4) -> everything through tile t+1 landed (keeps t+2 A in flight);
    //          BARRIER makes all waves' staged slices visible; then read next b01,
    //          stage B<-t+2, MFMA mlo x n23, read next alo (regs freed by the MFMA).
    asm volatile("s_waitcnt vmcnt(4)" ::: "memory");
    __builtin_amdgcn_s_barrier();
    __builtin_amdgcn_sched_barrier(0);
#pragma unroll
    for (int nf = 0; nf < 2; nf++)
#pragma unroll
      for (int ks = 0; ks < 2; ks++)
        b01[nf][ks] = FRAG(1, nbf, wn * 64 + nf * 16 + l16, ks * 64 + quad * 16);
    STAGE(B, 1, bfi, 0, n0, kt2);
    STAGE(B, 1, bfi, 1, n0 + 128, kt2);
    __builtin_amdgcn_sched_barrier(0);
    __builtin_amdgcn_s_setprio(1);
#pragma unroll
    for (int mf = 0; mf < 4; mf++)
#pragma unroll
      for (int nf = 0; nf < 2; nf++)
#pragma unroll
        for (int ks = 0; ks < 2; ks++)
          acc[mf][2 + nf] = __builtin_amdgcn_mfma_f32_16x16x32_bf16(alo[mf][ks], b23[nf][ks], acc[mf][2 + nf], 0, 0, 0);
    __builtin_amdgcn_s_setprio(0);
    __builtin_amdgcn_sched_barrier(0);
#pragma unroll
    for (int mf = 0; mf < 4; mf++)
#pragma unroll
      for (int ks = 0; ks < 2; ks++)
        alo[mf][ks] = FRAG(0, nbf, wm * 128 + mf * 16 + l16, ks * 64 + quad * 16);
    __builtin_amdgcn_s_barrier();
    __builtin_amdgcn_sched_barrier(0);
  }

  // epilogue
#pragma unroll
  for (int mf = 0; mf < 8; mf++)
#pragma unroll
    for (int nf = 0; nf < 4; nf++) {
      int col = n0 + wn * 64 + nf * 16 + l16;
#pragma unroll
      for (int r = 0; r < 4; r++) {
        int row = m0 + wm * 128 + mf * 16 + quad * 4 + r;
        store_cvt(&C[(size_t)row * N + col], acc[mf][nf][r]);
      }
    }
}

// ---------------- RMSNorm + RoPE: one wave per (token, slot) row ----------------
// rows = slot*8192 + token, slots 0..19 (16 q + 4 k). V is handled by transpose_v.
// Lane holds d=lane and d=lane+64 — rope partner is in-lane, one sincos per lane.
__global__ __launch_bounds__(256) void norm_rope(const bf16* __restrict__ qkv,
                                                 bf16* __restrict__ qb,
                                                 bf16* __restrict__ kb) {
  const int lane = threadIdx.x & 63;
  const int gw = (blockIdx.x * 256 + threadIdx.x) >> 6;
  const int nw = (gridDim.x * 256) >> 6;
  const float inv_freq = __expf(-(float)lane * (9.210340371976184f / 64.0f));
  for (int row = gw; row < 20 * 8192; row += nw) {
    const int slot = row >> 13, token = row & 8191;
    const int b = token >> 11, t = token & 2047;
    const bf16* src = qkv + (size_t)token * 3072 + slot * 128;
    float x1 = __bfloat162float(src[lane]);
    float x2 = __bfloat162float(src[lane + 64]);
    float ss = x1 * x1 + x2 * x2;
#pragma unroll
    for (int m = 1; m < 64; m <<= 1) ss += __shfl_xor(ss, m, 64);
    float rinv = rsqrtf(ss * (1.0f / 128.0f) + 1.1920929e-7f);
    x1 *= rinv; x2 *= rinv;
    float c, s;
    __sincosf((float)t * inv_freq, &s, &c);
    float o1 = x1 * c + x2 * s;
    float o2 = x2 * c - x1 * s;
    bf16* dst;
    if (slot < 16) {
      o1 *= 0.08838834764831845f;  // fold 1/sqrt(D) into q
      o2 *= 0.08838834764831845f;
      dst = qb + (((size_t)(b * 16 + slot)) * 2048 + t) * 128;
    } else {
      dst = kb + (((size_t)(b * 4 + (slot - 16))) * 2048 + t) * 128;
    }
    dst[lane] = __float2bfloat16(o1);
    dst[lane + 64] = __float2bfloat16(o2);
  }
}

// ---------------- V transpose straight from qkv: -> (s, d, t), s = b*4+hkv ----------------
__global__ __launch_bounds__(256) void transpose_v(const bf16* __restrict__ qkv,
                                                   bf16* __restrict__ vout) {
  __shared__ __align__(16) bf16 til[64][144];
  const int tid = threadIdx.x;
  const int s = blockIdx.y;                 // b*4 + hkv
  const int b = s >> 2, hkv = s & 3;
  const bf16* src = qkv + ((size_t)(b * 2048 + blockIdx.x * 64)) * 3072 + 2560 + hkv * 128;
  bf16* dst = vout + (size_t)s * 128 * 2048 + blockIdx.x * 64;
#pragma unroll
  for (int p = 0; p < 4; p++) {
    int idx = p * 256 + tid;
    *(uint4*)&til[idx >> 4][(idx & 15) * 8] =
        *(const uint4*)&src[(size_t)(idx >> 4) * 3072 + (idx & 15) * 8];
  }
  __syncthreads();
  const int ds = tid & 127;
  const int hs = tid >> 7;
#pragma unroll
  for (int p = 0; p < 4; p++) {
    int c8 = (p * 2 + hs) * 8;
    short8 v;
#pragma unroll
    for (int j = 0; j < 8; j++) v[j] = *(const short*)&til[c8 + j][ds];
    *(short8*)&dst[(size_t)ds * 2048 + c8] = v;
  }
}

// ---------------- causal GQA flash attention (persistent, balanced) ----------------
// 512 blocks = exactly 2/CU. Block i processes items {i, 1023-i}; item = qt*64 + bh.
// qt pairs sum to 15 => every block runs exactly 34 K-tiles. Fixed-shift softmax.
__global__ __launch_bounds__(512, 4) void flash_attn(const bf16* __restrict__ qb,
                                                     const bf16* __restrict__ kb,
                                                     const bf16* __restrict__ vtg,
                                                     bf16* __restrict__ attnb) {
  __shared__ __align__(16) bf16 Ks[64][136];    // 17.4 KB
  __shared__ __align__(16) bf16 Vt[128][72];    // 18.4 KB  [d][t]
  __shared__ __align__(16) bf16 Ps[8][16][72];  // 18.4 KB  per-wave slab

  const int tid = threadIdx.x;
  const int w = tid >> 6, lane = tid & 63;
  const int quad = lane >> 4, l16 = lane & 15;
  const int krow = tid >> 4, kc8 = (tid & 15) * 8;
  const int vrow = tid >> 3, vc8 = (tid & 7) * 8;

  for (int it = 0; it < 2; it++) {
    const int item = it == 0 ? blockIdx.x : 1023 - blockIdx.x;
    const int qt = item >> 6, bh = item & 63;
    const int b = bh >> 4, h = bh & 15, hkv = h >> 2;
    const int q0 = qt * 128;
    const bf16* Q  = qb  + ((size_t)(b * 16 + h) * 2048 + q0) * 128;
    const bf16* Kp = kb  + (size_t)(b * 4 + hkv) * 2048 * 128;
    const bf16* Vg = vtg + (size_t)(b * 4 + hkv) * 128 * 2048;
    const int qw = q0 + w * 16;

    // Q fragments (A-layout), pre-scaled by 1/sqrt(D)
    short8 aq[4];
#pragma unroll
    for (int dk = 0; dk < 4; dk++)
      aq[dk] = *(const short8*)&Q[(size_t)(w * 16 + l16) * 128 + dk * 32 + quad * 8];

    f32x4 o[8] = {};
    float l_i[4] = {0.f, 0.f, 0.f, 0.f};

    const int ntiles = 2 * qt + 2;
    uint4 ka0 = *(const uint4*)&Kp[(size_t)krow * 128 + kc8];
    uint4 ka1 = *(const uint4*)&Kp[(size_t)(krow + 32) * 128 + kc8];
    uint4 va0 = *(const uint4*)&Vg[(size_t)vrow * 2048 + vc8];
    uint4 va1 = *(const uint4*)&Vg[(size_t)(vrow + 64) * 2048 + vc8];

    for (int kt = 0; kt < ntiles; kt++) {
      const int kv0 = kt * 64;
      *(uint4*)&Ks[krow][kc8]      = ka0;
      *(uint4*)&Ks[krow + 32][kc8] = ka1;
      *(uint4*)&Vt[vrow][vc8]      = va0;
      *(uint4*)&Vt[vrow + 64][vc8] = va1;
      __syncthreads();

      // prefetch next tile; flies during compute
      const int nkv0 = min(kv0 + 64, (ntiles - 1) * 64);
      ka0 = *(const uint4*)&Kp[(size_t)(nkv0 + krow) * 128 + kc8];
      ka1 = *(const uint4*)&Kp[(size_t)(nkv0 + krow + 32) * 128 + kc8];
      va0 = *(const uint4*)&Vg[(size_t)vrow * 2048 + nkv0 + vc8];
      va1 = *(const uint4*)&Vg[(size_t)(vrow + 64) * 2048 + nkv0 + vc8];

      if (kv0 <= qw + 15) {  // wave-uniform causal skip
        f32x4 s[4] = {};
#pragma unroll
        for (int nt = 0; nt < 4; nt++)
#pragma unroll
          for (int dk = 0; dk < 4; dk++) {
            short8 bk = *(const short8*)&Ks[nt * 16 + l16][dk * 32 + quad * 8];
            s[nt] = __builtin_amdgcn_mfma_f32_16x16x32_bf16(aq[dk], bk, s[nt], 0, 0, 0);
          }

        // fixed-shift softmax: RMS-normed q,k => |s| <= sqrt(128) < 12
        const bool dtile = (kv0 + 63 > qw);
        const int qrow = qw + quad * 4;
#pragma unroll
        for (int nt = 0; nt < 4; nt++) {
          const int kcol = kv0 + nt * 16 + l16;
#pragma unroll
          for (int r = 0; r < 4; r++) {
            float p = __expf(s[nt][r] - 12.0f);
            if (dtile && kcol > qrow + r) p = 0.f;
            l_i[r] += p;
            Ps[w][quad * 4 + r][nt * 16 + l16] = __float2bfloat16(p);
          }
        }
        __threadfence_block();  // intra-wave RAW on per-wave Ps slab

        short8 ap[2];
#pragma unroll
        for (int kk = 0; kk < 2; kk++)
          ap[kk] = *(const short8*)&Ps[w][l16][kk * 32 + quad * 8];
#pragma unroll
        for (int vt = 0; vt < 8; vt++)
#pragma unroll
          for (int kk = 0; kk < 2; kk++) {
            short8 bv = *(const short8*)&Vt[vt * 16 + l16][kk * 32 + quad * 8];
            o[vt] = __builtin_amdgcn_mfma_f32_16x16x32_bf16(ap[kk], bv, o[vt], 0, 0, 0);
          }
      }
      __syncthreads();
    }

    // epilogue: register-only (safe to overlap with next item's staging)
#pragma unroll
    for (int r = 0; r < 4; r++) {
#pragma unroll
      for (int mm = 1; mm < 16; mm <<= 1) l_i[r] += __shfl_xor(l_i[r], mm, 64);
    }
#pragma unroll
    for (int r = 0; r < 4; r++) {
      float inv = 1.0f / l_i[r];
      int trow = qw + quad * 4 + r;
      size_t base = ((size_t)b * 2048 + trow) * 2048 + h * 128;
#pragma unroll
      for (int vt = 0; vt < 8; vt++)
        attnb[base + vt * 16 + l16] = __float2bfloat16(o[vt][r] * inv);
    }
  }
}

__global__ void finalize(float* out) {
  if (threadIdx.x == 0 && blockIdx.x == 0) out[(size_t)8192 * 2048] = 0.0f;
}

extern "C" void kernel_launch(void* const* d_in, const int* in_sizes, int n_in,
                              void* d_out, int out_size, void* d_ws, size_t ws_size,
                              hipStream_t stream) {
  const float* x  = (const float*)d_in[0];
  const float* Wq = (const float*)d_in[1];
  const float* Wk = (const float*)d_in[2];
  const float* Wv = (const float*)d_in[3];
  const float* Wo = (const float*)d_in[4];
  float* out = (float*)d_out;

  char* ws = (char*)d_ws;
  bf16* xb    = (bf16*)(ws);               // 33.5 MB
  bf16* wqkv  = (bf16*)(ws + 33554432);    // 12.6 MB (dead after QKV gemm)
  bf16* vtb   = (bf16*)(ws + 33554432);    // 8.4 MB, aliases wqkv
  bf16* wob   = (bf16*)(ws + 46137344);    // 8.4 MB
  bf16* qkvb  = (bf16*)(ws + 54525952);    // 50.3 MB
  bf16* qb    = (bf16*)(ws + 104857600);   // 33.5 MB
  bf16* kb    = (bf16*)(ws + 138412032);   // 8.4 MB
  bf16* attnb = qkvb;                      // alias: qkv dead after attention inputs built

  cast_f32_bf16<<<16384, 256, 0, stream>>>((const float4*)x,  (unsigned long long*)xb, 4194304);
  cast_f32_bf16<<<4096,  256, 0, stream>>>((const float4*)Wq, (unsigned long long*)wqkv, 1048576);
  cast_f32_bf16<<<1024,  256, 0, stream>>>((const float4*)Wk, (unsigned long long*)(wqkv + 2048 * 2048), 262144);
  cast_f32_bf16<<<1024,  256, 0, stream>>>((const float4*)Wv, (unsigned long long*)(wqkv + 2560 * 2048), 262144);
  cast_f32_bf16<<<4096,  256, 0, stream>>>((const float4*)Wo, (unsigned long long*)wob, 1048576);

  gemm_bt<bf16><<<dim3(12, 32), 512, 0, stream>>>(xb, wqkv, qkvb, 8192, 3072, 2048);
  norm_rope<<<4096, 256, 0, stream>>>(qkvb, qb, kb);
  transpose_v<<<dim3(32, 16), 256, 0, stream>>>(qkvb, vtb);
  flash_attn<<<512, 512, 0, stream>>>(qb, kb, vtb, attnb);
  gemm_bt<float><<<dim3(8, 32), 512, 0, stream>>>(attnb, wob, out, 8192, 2048, 2048);
  finalize<<<1, 64, 0, stream>>>(out);
}

// Round 4
// 468.190 us; speedup vs baseline: 1.1302x; 1.0003x over previous
//
#include <hip/hip_runtime.h>
#include <hip/hip_bf16.h>

typedef __attribute__((ext_vector_type(8))) short short8;
typedef __attribute__((ext_vector_type(4))) float f32x4;
typedef __attribute__((ext_vector_type(4))) unsigned int u32x4;
using bf16 = __hip_bfloat16;

__device__ inline unsigned short f2bfu(float x) {
  bf16 h = __float2bfloat16(x);
  return __builtin_bit_cast(unsigned short, h);
}

// async global->LDS 16B copy (lands at wave-uniform base + lane*16)
__device__ __forceinline__ void gll16(const void* g, void* l) {
  __builtin_amdgcn_global_load_lds(
      (const __attribute__((address_space(1))) unsigned int*)g,
      (__attribute__((address_space(3))) unsigned int*)l, 16, 0, 0);
}

// ---------------- cast fp32 -> bf16, 4 elems/thread ----------------
__global__ __launch_bounds__(256) void cast_f32_bf16(const float4* __restrict__ src,
                                                     unsigned long long* __restrict__ dst,
                                                     int n4) {
  int i = blockIdx.x * 256 + threadIdx.x;
  if (i >= n4) return;
  float4 v = src[i];
  unsigned long long r = (unsigned long long)f2bfu(v.x)
                       | ((unsigned long long)f2bfu(v.y) << 16)
                       | ((unsigned long long)f2bfu(v.z) << 32)
                       | ((unsigned long long)f2bfu(v.w) << 48);
  dst[i] = r;
}

// ---------------- GEMM: C[M,N] = A[M,K] * B[N,K]^T ----------------
// 256x256 tile, BK=64, 8 waves (2Mx4N). Read-ahead pipelined 4-phase schedule:
// ds_reads for phase i+1 issued in phase i (counted lgkmcnt), staging 2 K-tiles
// deep (counted vmcnt(4), never drained to 0 in-loop). Cross-wave visibility of
// staged tiles: every vmcnt drain is followed by s_barrier BEFORE any wave reads
// the staged region. XOR-swizzled LDS via pre-swizzled global_load_lds sources.
__device__ inline void store_cvt(float* p, float v) { *p = v; }
__device__ inline void store_cvt(bf16* p, float v) { *p = __float2bfloat16(v); }

template <typename OutT>
__global__ __launch_bounds__(512, 2) void gemm_bt(const bf16* __restrict__ A,
                                                  const bf16* __restrict__ B,
                                                  OutT* __restrict__ C,
                                                  int M, int N, int K) {
  __shared__ __align__(16) bf16 lds[2][2][256 * 64];  // [op A/B][dbuf][256 rows][64 k] = 128 KiB
  const int tid = threadIdx.x;
  const int wave = tid >> 6, lane = tid & 63;
  const int wm = wave >> 2, wn = wave & 3;          // 2 M-waves x 4 N-waves; per-wave 128x64 out
  const int quad = lane >> 4, l16 = lane & 15;

  // XCD-aware swizzle (nwg % 8 == 0 for all our shapes -> simple form is bijective)
  const int nwg = gridDim.x * gridDim.y;
  int lin = blockIdx.y * gridDim.x + blockIdx.x;
  lin = (lin & 7) * (nwg >> 3) + (lin >> 3);
  const int n0 = (lin % gridDim.x) << 8;
  const int m0 = (lin / gridDim.x) << 8;

  // staging pattern: pass p writes LDS chunk (p*512+tid)*16 LINEARLY (gll requirement);
  // source is pre-swizzled with the same involution the reads use: byte ^= (row&7)<<4.
  int off_el[2], dst_b[2];
#pragma unroll
  for (int p = 0; p < 2; p++) {
    int d = (p * 512 + tid) * 16;
    int dl = d ^ (((d >> 7) & 7) << 4);
    off_el[p] = (dl >> 7) * K + ((dl & 127) >> 1);
    dst_b[p] = d;
  }

  auto STAGE = [&](const bf16* __restrict__ P, int op, int bfi, int half, int rowBase, int kt) {
    const bf16* src = P + (size_t)rowBase * K + kt;
    char* dst = (char*)&lds[op][bfi][half * 8192];
    gll16(src + off_el[0], dst + dst_b[0]);
    gll16(src + off_el[1], dst + dst_b[1]);
  };
  auto FRAG = [&](int op, int bfi, int row, int cb) -> short8 {
    int byteoff = ((row << 7) + cb) ^ ((row & 7) << 4);
    return *(const short8*)((const char*)&lds[op][bfi][0] + byteoff);
  };

  f32x4 acc[8][4] = {};
  const int nkt = K >> 6;

  short8 alo[4][2], ahi[4][2], b01[2][2], b23[2][2];

  // prologue: stage tile0 + tile1 fully (16 loads); wait tile0 + barrier; preload alo,b01.
  STAGE(A, 0, 0, 0, m0, 0);
  STAGE(A, 0, 0, 1, m0 + 128, 0);
  STAGE(B, 1, 0, 0, n0, 0);
  STAGE(B, 1, 0, 1, n0 + 128, 0);
  {
    const int k1 = (nkt > 1) ? 64 : 0;
    STAGE(A, 0, 1, 0, m0, k1);
    STAGE(A, 0, 1, 1, m0 + 128, k1);
    STAGE(B, 1, 1, 0, n0, k1);
    STAGE(B, 1, 1, 1, n0 + 128, k1);
  }
  asm volatile("s_waitcnt vmcnt(8)" ::: "memory");
  __builtin_amdgcn_s_barrier();
  __builtin_amdgcn_sched_barrier(0);
#pragma unroll
  for (int mf = 0; mf < 4; mf++)
#pragma unroll
    for (int ks = 0; ks < 2; ks++)
      alo[mf][ks] = FRAG(0, 0, wm * 128 + mf * 16 + l16, ks * 64 + quad * 16);
#pragma unroll
  for (int nf = 0; nf < 2; nf++)
#pragma unroll
    for (int ks = 0; ks < 2; ks++)
      b01[nf][ks] = FRAG(1, 0, wn * 64 + nf * 16 + l16, ks * 64 + quad * 16);

  for (int t = 0; t < nkt; ++t) {
    const int bfi = t & 1, nbf = bfi ^ 1;
    const int kt2 = min(t + 2, nkt - 1) << 6;

    // ---- p0: issue ahi reads; MFMA mlo x n01 (alo,b01 drained by lgkm(8))
#pragma unroll
    for (int mf = 0; mf < 4; mf++)
#pragma unroll
      for (int ks = 0; ks < 2; ks++)
        ahi[mf][ks] = FRAG(0, bfi, wm * 128 + 64 + mf * 16 + l16, ks * 64 + quad * 16);
    asm volatile("s_waitcnt lgkmcnt(8)" ::: "memory");
    __builtin_amdgcn_sched_barrier(0);
    __builtin_amdgcn_s_setprio(1);
#pragma unroll
    for (int mf = 0; mf < 4; mf++)
#pragma unroll
      for (int nf = 0; nf < 2; nf++)
#pragma unroll
        for (int ks = 0; ks < 2; ks++)
          acc[mf][nf] = __builtin_amdgcn_mfma_f32_16x16x32_bf16(alo[mf][ks], b01[nf][ks], acc[mf][nf], 0, 0, 0);
    __builtin_amdgcn_s_setprio(0);
    __builtin_amdgcn_sched_barrier(0);
    __builtin_amdgcn_s_barrier();
    __builtin_amdgcn_sched_barrier(0);

    // ---- p1: issue b23 reads; MFMA mhi x n01 (ahi drained by lgkm(4))
#pragma unroll
    for (int nf = 0; nf < 2; nf++)
#pragma unroll
      for (int ks = 0; ks < 2; ks++)
        b23[nf][ks] = FRAG(1, bfi, wn * 64 + 32 + nf * 16 + l16, ks * 64 + quad * 16);
    asm volatile("s_waitcnt lgkmcnt(4)" ::: "memory");
    __builtin_amdgcn_sched_barrier(0);
    __builtin_amdgcn_s_setprio(1);
#pragma unroll
    for (int mf = 0; mf < 4; mf++)
#pragma unroll
      for (int nf = 0; nf < 2; nf++)
#pragma unroll
        for (int ks = 0; ks < 2; ks++)
          acc[4 + mf][nf] = __builtin_amdgcn_mfma_f32_16x16x32_bf16(ahi[mf][ks], b01[nf][ks], acc[4 + mf][nf], 0, 0, 0);
    __builtin_amdgcn_s_setprio(0);
    __builtin_amdgcn_sched_barrier(0);
    __builtin_amdgcn_s_barrier();
    __builtin_amdgcn_sched_barrier(0);

    // ---- p2: stage A<-t+2 (A[bfi] fully consumed: alo pre-loop/p3, ahi drained p1,
    //          p1 end barrier passed); MFMA mhi x n23 (b23 drained by lgkm(0))
    STAGE(A, 0, bfi, 0, m0, kt2);
    STAGE(A, 0, bfi, 1, m0 + 128, kt2);
    asm volatile("s_waitcnt lgkmcnt(0)" ::: "memory");
    __builtin_amdgcn_sched_barrier(0);
    __builtin_amdgcn_s_setprio(1);
#pragma unroll
    for (int mf = 0; mf < 4; mf++)
#pragma unroll
      for (int nf = 0; nf < 2; nf++)
#pragma unroll
        for (int ks = 0; ks < 2; ks++)
          acc[4 + mf][2 + nf] = __builtin_amdgcn_mfma_f32_16x16x32_bf16(ahi[mf][ks], b23[nf][ks], acc[4 + mf][2 + nf], 0, 0, 0);
    __builtin_amdgcn_s_setprio(0);
    __builtin_amdgcn_sched_barrier(0);
    __builtin_amdgcn_s_barrier();
    __builtin_amdgcn_sched_barrier(0);

    // ---- p3: vmcnt(4) -> everything through tile t+1 landed (keeps t+2 A in flight);
    //          BARRIER makes all waves' staged slices visible; then read next b01,
    //          stage B<-t+2, MFMA mlo x n23, read next alo (regs freed by the MFMA).
    asm volatile("s_waitcnt vmcnt(4)" ::: "memory");
    __builtin_amdgcn_s_barrier();
    __builtin_amdgcn_sched_barrier(0);
#pragma unroll
    for (int nf = 0; nf < 2; nf++)
#pragma unroll
      for (int ks = 0; ks < 2; ks++)
        b01[nf][ks] = FRAG(1, nbf, wn * 64 + nf * 16 + l16, ks * 64 + quad * 16);
    STAGE(B, 1, bfi, 0, n0, kt2);
    STAGE(B, 1, bfi, 1, n0 + 128, kt2);
    __builtin_amdgcn_sched_barrier(0);
    __builtin_amdgcn_s_setprio(1);
#pragma unroll
    for (int mf = 0; mf < 4; mf++)
#pragma unroll
      for (int nf = 0; nf < 2; nf++)
#pragma unroll
        for (int ks = 0; ks < 2; ks++)
          acc[mf][2 + nf] = __builtin_amdgcn_mfma_f32_16x16x32_bf16(alo[mf][ks], b23[nf][ks], acc[mf][2 + nf], 0, 0, 0);
    __builtin_amdgcn_s_setprio(0);
    __builtin_amdgcn_sched_barrier(0);
#pragma unroll
    for (int mf = 0; mf < 4; mf++)
#pragma unroll
      for (int ks = 0; ks < 2; ks++)
        alo[mf][ks] = FRAG(0, nbf, wm * 128 + mf * 16 + l16, ks * 64 + quad * 16);
    __builtin_amdgcn_s_barrier();
    __builtin_amdgcn_sched_barrier(0);
  }

  // epilogue
#pragma unroll
  for (int mf = 0; mf < 8; mf++)
#pragma unroll
    for (int nf = 0; nf < 4; nf++) {
      int col = n0 + wn * 64 + nf * 16 + l16;
#pragma unroll
      for (int r = 0; r < 4; r++) {
        int row = m0 + wm * 128 + mf * 16 + quad * 4 + r;
        store_cvt(&C[(size_t)row * N + col], acc[mf][nf][r]);
      }
    }
}

// ---------------- RMSNorm + RoPE: one wave per (token, slot) row ----------------
// rows = slot*8192 + token, slots 0..19 (16 q + 4 k). V is handled by transpose_v.
// Lane holds d=lane and d=lane+64 — rope partner is in-lane, one sincos per lane.
__global__ __launch_bounds__(256) void norm_rope(const bf16* __restrict__ qkv,
                                                 bf16* __restrict__ qb,
                                                 bf16* __restrict__ kb) {
  const int lane = threadIdx.x & 63;
  const int gw = (blockIdx.x * 256 + threadIdx.x) >> 6;
  const int nw = (gridDim.x * 256) >> 6;
  const float inv_freq = __expf(-(float)lane * (9.210340371976184f / 64.0f));
  for (int row = gw; row < 20 * 8192; row += nw) {
    const int slot = row >> 13, token = row & 8191;
    const int b = token >> 11, t = token & 2047;
    const bf16* src = qkv + (size_t)token * 3072 + slot * 128;
    float x1 = __bfloat162float(src[lane]);
    float x2 = __bfloat162float(src[lane + 64]);
    float ss = x1 * x1 + x2 * x2;
#pragma unroll
    for (int m = 1; m < 64; m <<= 1) ss += __shfl_xor(ss, m, 64);
    float rinv = rsqrtf(ss * (1.0f / 128.0f) + 1.1920929e-7f);
    x1 *= rinv; x2 *= rinv;
    float c, s;
    __sincosf((float)t * inv_freq, &s, &c);
    float o1 = x1 * c + x2 * s;
    float o2 = x2 * c - x1 * s;
    bf16* dst;
    if (slot < 16) {
      o1 *= 0.08838834764831845f;  // fold 1/sqrt(D) into q
      o2 *= 0.08838834764831845f;
      dst = qb + (((size_t)(b * 16 + slot)) * 2048 + t) * 128;
    } else {
      dst = kb + (((size_t)(b * 4 + (slot - 16))) * 2048 + t) * 128;
    }
    dst[lane] = __float2bfloat16(o1);
    dst[lane + 64] = __float2bfloat16(o2);
  }
}

// ---------------- V transpose straight from qkv: -> (s, d, t), s = b*4+hkv ----------------
__global__ __launch_bounds__(256) void transpose_v(const bf16* __restrict__ qkv,
                                                   bf16* __restrict__ vout) {
  __shared__ __align__(16) bf16 til[64][144];
  const int tid = threadIdx.x;
  const int s = blockIdx.y;                 // b*4 + hkv
  const int b = s >> 2, hkv = s & 3;
  const bf16* src = qkv + ((size_t)(b * 2048 + blockIdx.x * 64)) * 3072 + 2560 + hkv * 128;
  bf16* dst = vout + (size_t)s * 128 * 2048 + blockIdx.x * 64;
#pragma unroll
  for (int p = 0; p < 4; p++) {
    int idx = p * 256 + tid;
    *(uint4*)&til[idx >> 4][(idx & 15) * 8] =
        *(const uint4*)&src[(size_t)(idx >> 4) * 3072 + (idx & 15) * 8];
  }
  __syncthreads();
  const int ds = tid & 127;
  const int hs = tid >> 7;
#pragma unroll
  for (int p = 0; p < 4; p++) {
    int c8 = (p * 2 + hs) * 8;
    short8 v;
#pragma unroll
    for (int j = 0; j < 8; j++) v[j] = *(const short*)&til[c8 + j][ds];
    *(short8*)&dst[(size_t)ds * 2048 + c8] = v;
  }
}

// ---------------- causal GQA flash attention (persistent, balanced) ----------------
// 512 blocks = exactly 2/CU. Block i processes items {i, 1023-i}; item = qt*64 + bh.
// qt pairs sum to 15 => every block runs exactly 34 K-tiles.
// Swapped QK^T (S^T = mfma(K,Q)) -> P stays in registers (q = l16 per lane);
// PV A-fragments built with in-wave shfl (no Ps LDS, no threadfence, no conflicts).
// Fixed-shift softmax: RMS-normed q,k => |s| <= sqrt(128) < 12.
__global__ __launch_bounds__(512, 4) void flash_attn(const bf16* __restrict__ qb,
                                                     const bf16* __restrict__ kb,
                                                     const bf16* __restrict__ vtg,
                                                     bf16* __restrict__ attnb) {
  __shared__ __align__(16) bf16 Ks[64][136];    // 17.4 KB
  __shared__ __align__(16) bf16 Vt[128][72];    // 18.4 KB  [d][t]

  const int tid = threadIdx.x;
  const int w = tid >> 6, lane = tid & 63;
  const int quad = lane >> 4, l16 = lane & 15;
  const int krow = tid >> 4, kc8 = (tid & 15) * 8;
  const int vrow = tid >> 3, vc8 = (tid & 7) * 8;
  // shfl source lanes for PV A-frag assembly (consumer quad q pulls from quads
  // 2(q&1) and 2(q&1)+1; selects nt-class by q>>1)
  const int srcA = ((quad & 1) << 5) + l16;
  const int srcB = srcA + 16;

  for (int it = 0; it < 2; it++) {
    const int item = it == 0 ? blockIdx.x : 1023 - blockIdx.x;
    const int qt = item >> 6, bh = item & 63;
    const int b = bh >> 4, h = bh & 15, hkv = h >> 2;
    const int q0 = qt * 128;
    const bf16* Q  = qb  + ((size_t)(b * 16 + h) * 2048 + q0) * 128;
    const bf16* Kp = kb  + (size_t)(b * 4 + hkv) * 2048 * 128;
    const bf16* Vg = vtg + (size_t)(b * 4 + hkv) * 128 * 2048;
    const int qw = q0 + w * 16;
    const int qrow_l = qw + l16;   // this lane's q-row (swapped-QK: q = l16)

    // Q fragments, pre-scaled by 1/sqrt(D); used as B-operand (col=l16 ↔ q)
    short8 aq[4];
#pragma unroll
    for (int dk = 0; dk < 4; dk++)
      aq[dk] = *(const short8*)&Q[(size_t)(w * 16 + l16) * 128 + dk * 32 + quad * 8];

    f32x4 o[8] = {};
    float l_part = 0.f;  // sum of this lane's P values (all for q = l16)

    const int ntiles = 2 * qt + 2;
    uint4 ka0 = *(const uint4*)&Kp[(size_t)krow * 128 + kc8];
    uint4 ka1 = *(const uint4*)&Kp[(size_t)(krow + 32) * 128 + kc8];
    uint4 va0 = *(const uint4*)&Vg[(size_t)vrow * 2048 + vc8];
    uint4 va1 = *(const uint4*)&Vg[(size_t)(vrow + 64) * 2048 + vc8];

    for (int kt = 0; kt < ntiles; kt++) {
      const int kv0 = kt * 64;
      *(uint4*)&Ks[krow][kc8]      = ka0;
      *(uint4*)&Ks[krow + 32][kc8] = ka1;
      *(uint4*)&Vt[vrow][vc8]      = va0;
      *(uint4*)&Vt[vrow + 64][vc8] = va1;
      __syncthreads();

      // prefetch next tile; flies during compute
      const int nkv0 = min(kv0 + 64, (ntiles - 1) * 64);
      ka0 = *(const uint4*)&Kp[(size_t)(nkv0 + krow) * 128 + kc8];
      ka1 = *(const uint4*)&Kp[(size_t)(nkv0 + krow + 32) * 128 + kc8];
      va0 = *(const uint4*)&Vg[(size_t)vrow * 2048 + nkv0 + vc8];
      va1 = *(const uint4*)&Vg[(size_t)(vrow + 64) * 2048 + nkv0 + vc8];

      if (kv0 <= qw + 15) {  // wave-uniform causal skip
        // S^T = K·Q^T: A = K-frag (row = l16 ↔ k-row), B = Q-frag (col = l16 ↔ q)
        f32x4 s[4] = {};
#pragma unroll
        for (int nt = 0; nt < 4; nt++)
#pragma unroll
          for (int dk = 0; dk < 4; dk++) {
            short8 bk = *(const short8*)&Ks[nt * 16 + l16][dk * 32 + quad * 8];
            s[nt] = __builtin_amdgcn_mfma_f32_16x16x32_bf16(bk, aq[dk], s[nt], 0, 0, 0);
          }

        // softmax in-register: lane holds P[k = kv0+nt*16+quad*4+r][q = l16]
        const bool dtile = (kv0 + 63 > qw);
        unsigned pk[4][2];
#pragma unroll
        for (int nt = 0; nt < 4; nt++) {
          const int kbase = kv0 + nt * 16 + quad * 4;
          float p[4];
#pragma unroll
          for (int r = 0; r < 4; r++) {
            float pv = __expf(s[nt][r] - 12.0f);
            if (dtile && (kbase + r) > qrow_l) pv = 0.f;
            l_part += pv;
            p[r] = pv;
          }
          pk[nt][0] = (unsigned)f2bfu(p[0]) | ((unsigned)f2bfu(p[1]) << 16);
          pk[nt][1] = (unsigned)f2bfu(p[2]) | ((unsigned)f2bfu(p[3]) << 16);
        }

        // build PV A-frags: ap[kk] covers k = kv0 + kk*32 + quad*8 + 0..7
        short8 ap[2];
#pragma unroll
        for (int kk = 0; kk < 2; kk++) {
          unsigned aLo0 = (unsigned)__shfl((int)pk[2 * kk][0], srcA, 64);
          unsigned aLo1 = (unsigned)__shfl((int)pk[2 * kk][1], srcA, 64);
          unsigned aHi0 = (unsigned)__shfl((int)pk[2 * kk + 1][0], srcA, 64);
          unsigned aHi1 = (unsigned)__shfl((int)pk[2 * kk + 1][1], srcA, 64);
          unsigned bLo0 = (unsigned)__shfl((int)pk[2 * kk][0], srcB, 64);
          unsigned bLo1 = (unsigned)__shfl((int)pk[2 * kk][1], srcB, 64);
          unsigned bHi0 = (unsigned)__shfl((int)pk[2 * kk + 1][0], srcB, 64);
          unsigned bHi1 = (unsigned)__shfl((int)pk[2 * kk + 1][1], srcB, 64);
          u32x4 wv;
          wv[0] = (quad & 2) ? aHi0 : aLo0;
          wv[1] = (quad & 2) ? aHi1 : aLo1;
          wv[2] = (quad & 2) ? bHi0 : bLo0;
          wv[3] = (quad & 2) ? bHi1 : bLo1;
          ap[kk] = __builtin_bit_cast(short8, wv);
        }

#pragma unroll
        for (int vt = 0; vt < 8; vt++)
#pragma unroll
          for (int kk = 0; kk < 2; kk++) {
            short8 bv = *(const short8*)&Vt[vt * 16 + l16][kk * 32 + quad * 8];
            o[vt] = __builtin_amdgcn_mfma_f32_16x16x32_bf16(ap[kk], bv, o[vt], 0, 0, 0);
          }
      }
      __syncthreads();
    }

    // epilogue: reduce l across quads (all lanes then hold L[q = l16]), then
    // redistribute to accumulator rows (o row r corresponds to q = quad*4+r).
    l_part += __shfl_xor(l_part, 16, 64);
    l_part += __shfl_xor(l_part, 32, 64);
    float inv[4];
#pragma unroll
    for (int r = 0; r < 4; r++)
      inv[r] = 1.0f / __shfl(l_part, quad * 4 + r, 64);
#pragma unroll
    for (int r = 0; r < 4; r++) {
      int trow = qw + quad * 4 + r;
      size_t base = ((size_t)b * 2048 + trow) * 2048 + h * 128;
#pragma unroll
      for (int vt = 0; vt < 8; vt++)
        attnb[base + vt * 16 + l16] = __float2bfloat16(o[vt][r] * inv[r]);
    }
  }
}

__global__ void finalize(float* out) {
  if (threadIdx.x == 0 && blockIdx.x == 0) out[(size_t)8192 * 2048] = 0.0f;
}

extern "C" void kernel_launch(void* const* d_in, const int* in_sizes, int n_in,
                              void* d_out, int out_size, void* d_ws, size_t ws_size,
                              hipStream_t stream) {
  const float* x  = (const float*)d_in[0];
  const float* Wq = (const float*)d_in[1];
  const float* Wk = (const float*)d_in[2];
  const float* Wv = (const float*)d_in[3];
  const float* Wo = (const float*)d_in[4];
  float* out = (float*)d_out;

  char* ws = (char*)d_ws;
  bf16* xb    = (bf16*)(ws);               // 33.5 MB
  bf16* wqkv  = (bf16*)(ws + 33554432);    // 12.6 MB (dead after QKV gemm)
  bf16* vtb   = (bf16*)(ws + 33554432);    // 8.4 MB, aliases wqkv
  bf16* wob   = (bf16*)(ws + 46137344);    // 8.4 MB
  bf16* qkvb  = (bf16*)(ws + 54525952);    // 50.3 MB
  bf16* qb    = (bf16*)(ws + 104857600);   // 33.5 MB
  bf16* kb    = (bf16*)(ws + 138412032);   // 8.4 MB
  bf16* attnb = qkvb;                      // alias: qkv dead after attention inputs built

  cast_f32_bf16<<<16384, 256, 0, stream>>>((const float4*)x,  (unsigned long long*)xb, 4194304);
  cast_f32_bf16<<<4096,  256, 0, stream>>>((const float4*)Wq, (unsigned long long*)wqkv, 1048576);
  cast_f32_bf16<<<1024,  256, 0, stream>>>((const float4*)Wk, (unsigned long long*)(wqkv + 2048 * 2048), 262144);
  cast_f32_bf16<<<1024,  256, 0, stream>>>((const float4*)Wv, (unsigned long long*)(wqkv + 2560 * 2048), 262144);
  cast_f32_bf16<<<4096,  256, 0, stream>>>((const float4*)Wo, (unsigned long long*)wob, 1048576);

  gemm_bt<bf16><<<dim3(12, 32), 512, 0, stream>>>(xb, wqkv, qkvb, 8192, 3072, 2048);
  norm_rope<<<4096, 256, 0, stream>>>(qkvb, qb, kb);
  transpose_v<<<dim3(32, 16), 256, 0, stream>>>(qkvb, vtb);
  flash_attn<<<512, 512, 0, stream>>>(qb, kb, vtb, attnb);
  gemm_bt<float><<<dim3(8, 32), 512, 0, stream>>>(attnb, wob, out, 8192, 2048, 2048);
  finalize<<<1, 64, 0, stream>>>(out);
}